// Round 5
// baseline (3884.369 us; speedup 1.0000x reference)
//
#include <hip/hip_runtime.h>
#include <hip/hip_bf16.h>

// MyRnn: h_t = tanh(emb[idx_t] @ W_xh + b_h + h_{t-1} @ W_hh), 80 steps,
// out = sigmoid(h_80 @ W_out + b_out).
//
// R6b: ROWS=64 / 32 blocks, conservative launch. R5 proved no scratch issue
// (named-reg kernel, identical counters) -- the bottleneck is the per-CU
// WEIGHT RE-STREAM: 640KB of B-frags from L2 every step (11.4k cy at
// ~56B/cy/CU) vs only 3.1k cy of MFMA work at ROWS=16, plus L2 thrash
// (16 blocks/XCD x 640KB = 10.2MB vs 4MB L2 -> FETCH 2GB to L3/HBM).
// Fix: 4x work per weight-byte. 64 batch rows/block (4 m-tiles/wave),
// 32 blocks: per-CU MFMA 12.4k cy >= stream 11.4k cy, 4 blocks/XCD ->
// weights L2-resident, no thrash.
// R6 (container died) suspects removed: NO hipFuncSetAttribute (graph-
// capture tripwire), NO 160KB dynamic LDS. Static 96KB LDS: single h
// buffer (64KB) + x dbuf (2x16KB); read-phase | barrier | write-phase |
// barrier per step. Regs: 16 f32x4 acc + depth-2 pipe ~150 live;
// amdgpu_waves_per_eu(2,2) (= the real occupancy at 96KB LDS) for the
// 256-VGPR budget.

#define T_LEN   80
#define EMB_D   100
#define UNITS   512
#define ROWS    64
#define NBLK    32
#define NTHR    512

typedef __bf16 bf16x8 __attribute__((ext_vector_type(8)));
typedef float  f32x4  __attribute__((ext_vector_type(4)));

__device__ __forceinline__ float fast_tanh(float x) {
    float e = __builtin_amdgcn_exp2f(x * 2.8853900817779268f);
    return 1.0f - 2.0f * __builtin_amdgcn_rcpf(1.0f + e);
}

// ---- prep: rewrite weights into MFMA-fragment order in d_ws ----
// FW[w][ks][nt][lane][8]: elem j = Whh[ks*32 + (lane>>4)*8 + j][w*64 + nt*16 + (lane&15)]
// FX[w][ks][nt][lane][8]: same from Wxh, k >= 100 -> 0
__global__ void prep_kernel(const float* __restrict__ Whh,
                            const float* __restrict__ Wxh,
                            __bf16* __restrict__ FW, __bf16* __restrict__ FX) {
    const int f = blockIdx.x * 256 + threadIdx.x;
    if (f < 32768) {
        const int lane = f & 63, nt = (f >> 6) & 3, ks = (f >> 8) & 15, w = f >> 12;
        const int c  = (w << 6) + (nt << 4) + (lane & 15);
        const int kb = (ks << 5) + ((lane >> 4) << 3);
        __bf16* d = FW + (size_t)f * 8;
        #pragma unroll
        for (int j = 0; j < 8; ++j)
            d[j] = (__bf16)Whh[(kb + j) * UNITS + c];
    } else {
        const int f2 = f - 32768;
        const int lane = f2 & 63, nt = (f2 >> 6) & 3, ks = (f2 >> 8) & 3, w = f2 >> 10;
        const int c  = (w << 6) + (nt << 4) + (lane & 15);
        const int kb = (ks << 5) + ((lane >> 4) << 3);
        __bf16* d = FX + (size_t)f2 * 8;
        #pragma unroll
        for (int j = 0; j < 8; ++j)
            d[j] = (kb + j < EMB_D) ? (__bf16)Wxh[(kb + j) * UNITS + c] : (__bf16)0.0f;
    }
}

#define MF(A, B, C) __builtin_amdgcn_mfma_f32_16x16x32_bf16((A), (B), (C), 0, 0, 0)

// prefetch unified kstep KK's 4 B-frags into named slot P (KK literal)
#define PF(KK, P) do {                                                        \
    const __bf16* _p = ((KK) < 4) ? (fxp + ((KK) << 11))                      \
                                  : (fwp + (((KK) - 4) << 11));               \
    P##0 = *(const bf16x8*)(_p);                                              \
    P##1 = *(const bf16x8*)(_p + 512);                                        \
    P##2 = *(const bf16x8*)(_p + 1024);                                       \
    P##3 = *(const bf16x8*)(_p + 1536);                                       \
} while (0)

// A-frag for m-tile M at unified kstep KK (rows 16M+ln, swizzled LDS)
#define ALD(KK, M) ( ((KK) < 4)                                               \
    ? *(const bf16x8*)&xb_r[xbase + ((M) << 11) + (((KK) ^ kx) << 5)]         \
    : *(const bf16x8*)&hb[hbase + ((M) << 13) + ((((KK) - 4) ^ kx) << 5)] )

// consume kstep KK from slot P: 4 A-loads, 16 MFMAs (acc cNM: N=nt, M=mtile)
#define MM(KK, P) do {                                                        \
    const bf16x8 _a0 = ALD(KK, 0); const bf16x8 _a1 = ALD(KK, 1);             \
    const bf16x8 _a2 = ALD(KK, 2); const bf16x8 _a3 = ALD(KK, 3);             \
    c00 = MF(_a0, P##0, c00); c10 = MF(_a0, P##1, c10);                       \
    c20 = MF(_a0, P##2, c20); c30 = MF(_a0, P##3, c30);                       \
    c01 = MF(_a1, P##0, c01); c11 = MF(_a1, P##1, c11);                       \
    c21 = MF(_a1, P##2, c21); c31 = MF(_a1, P##3, c31);                       \
    c02 = MF(_a2, P##0, c02); c12 = MF(_a2, P##1, c12);                       \
    c22 = MF(_a2, P##2, c22); c32 = MF(_a2, P##3, c32);                       \
    c03 = MF(_a3, P##0, c03); c13 = MF(_a3, P##1, c13);                       \
    c23 = MF(_a3, P##2, c23); c33 = MF(_a3, P##3, c33);                       \
} while (0)

// write h' frag (NT_, M_): C/D layout col=ln, row=4q+i; XOR-swizzled LDS
#define HWR(NT_, M_, ACC) {                                                   \
    const int _cc = (wave << 3) + ((NT_) << 1) + (ln >> 3);                   \
    _Pragma("unroll")                                                         \
    for (int _i = 0; _i < 4; ++_i) {                                          \
        const int _rl = (q << 2) + _i;                                        \
        hb[((M_) << 13) + (_rl << 9) + (((_cc ^ (_rl & 7)) << 3) | e7)] =     \
            (__bf16)fast_tanh(ACC[_i]);                                       \
    }                                                                         \
}

// one timestep: read phase (hb + xb_r -> acc), barrier, write phase, barrier
#define STEP(XB_R) do {                                                       \
    const __bf16* const xb_r = (XB_R);                                        \
    f32x4 c00 = {bhv0, bhv0, bhv0, bhv0}; f32x4 c01 = c00, c02 = c00, c03 = c00; \
    f32x4 c10 = {bhv1, bhv1, bhv1, bhv1}; f32x4 c11 = c10, c12 = c10, c13 = c10; \
    f32x4 c20 = {bhv2, bhv2, bhv2, bhv2}; f32x4 c21 = c20, c22 = c20, c23 = c20; \
    f32x4 c30 = {bhv3, bhv3, bhv3, bhv3}; f32x4 c31 = c30, c32 = c30, c33 = c30; \
    MM(0,  pA); PF(2,  pA);  MM(1,  pB); PF(3,  pB);                          \
    MM(2,  pA); PF(4,  pA);  MM(3,  pB); PF(5,  pB);                          \
    MM(4,  pA); PF(6,  pA);  MM(5,  pB); PF(7,  pB);                          \
    MM(6,  pA); PF(8,  pA);  MM(7,  pB); PF(9,  pB);                          \
    MM(8,  pA); PF(10, pA);  MM(9,  pB); PF(11, pB);                          \
    MM(10, pA); PF(12, pA);  MM(11, pB); PF(13, pB);                          \
    MM(12, pA); PF(14, pA);  MM(13, pB); PF(15, pB);                          \
    MM(14, pA); PF(16, pA);  MM(15, pB); PF(17, pB);                          \
    MM(16, pA); PF(18, pA);  MM(17, pB); PF(19, pB);                          \
    MM(18, pA); PF(0,  pA);  MM(19, pB); PF(1,  pB);                          \
    __syncthreads();  /* all hb/xb reads done; staged x visible */            \
    HWR(0, 0, c00) HWR(0, 1, c01) HWR(0, 2, c02) HWR(0, 3, c03)               \
    HWR(1, 0, c10) HWR(1, 1, c11) HWR(1, 2, c12) HWR(1, 3, c13)               \
    HWR(2, 0, c20) HWR(2, 1, c21) HWR(2, 2, c22) HWR(2, 3, c23)               \
    HWR(3, 0, c30) HWR(3, 1, c31) HWR(3, 2, c32) HWR(3, 3, c33)               \
    __syncthreads();  /* h_t visible to all waves */                          \
} while (0)

__global__ __launch_bounds__(NTHR)
__attribute__((amdgpu_waves_per_eu(2, 2)))
void rnn_kernel(const int*   __restrict__ inputs,   // [2048][80]
                const float* __restrict__ emb,      // [35000][100]
                const float* __restrict__ bh,       // [512]
                const float* __restrict__ Wout,     // [512]
                const float* __restrict__ bout,     // [1]
                const __bf16* __restrict__ FW,      // frag-order Whh (ws)
                const __bf16* __restrict__ FX,      // frag-order Wxh (ws)
                float*       __restrict__ out)      // [2048]
{
    // static LDS, 96KB total:
    //   hb:  64 rows x 512 bf16, single buffer (read|barrier|write per step)
    //        XOR-swizzled 16B chunks: elem(m,k) = m*512 + (((k>>3)^(m&7))<<3) + (k&7)
    //   xb:  2 x (64 rows x 128 bf16), same swizzle, row stride 128
    __shared__ alignas(16) __bf16 hb[ROWS * UNITS];
    __shared__ alignas(16) __bf16 xbuf[2][ROWS * 128];

    const int tid  = threadIdx.x;
    const int wave = tid >> 6;       // 0..7 (owns cols [64w, 64w+64))
    const int lane = tid & 63;
    const int q    = lane >> 4;      // MFMA quad
    const int ln   = lane & 15;
    const int e7   = ln & 7;
    const int qa   = q ^ (e7 & 3);
    const int kx   = e7 >> 2;
    const int r0   = blockIdx.x * ROWS;

    const float bhv0 = bh[(wave << 6) + 0  + ln];
    const float bhv1 = bh[(wave << 6) + 16 + ln];
    const float bhv2 = bh[(wave << 6) + 32 + ln];
    const float bhv3 = bh[(wave << 6) + 48 + ln];

    const __bf16* const fxp = FX + (wave << 13) + (lane << 3);
    const __bf16* const fwp = FW + (wave << 15) + (lane << 3);
    const int xbase = (ln << 7) + (qa << 3);
    const int hbase = (ln << 9) + (qa << 3);

    // depth-2 W-stream pipeline: 8 named bf16x8 (32 VGPR)
    bf16x8 pA0, pA1, pA2, pA3;
    bf16x8 pB0, pB1, pB2, pB3;

    // zero h (65536 B) and both x buffers (32768 B; pad cols k>=100 stay 0)
    {
        int4 z; z.x = z.y = z.z = z.w = 0;
        int4* hp = (int4*)hb;
        #pragma unroll
        for (int i = 0; i < 8; ++i) hp[tid + i * NTHR] = z;
        int4* xp = (int4*)&xbuf[0][0];
        #pragma unroll
        for (int i = 0; i < 4; ++i) xp[tid + i * NTHR] = z;
    }
    __syncthreads();   // zero complete before stage() writes (cross-wave)

    // stage embedded x_t (bf16, swizzled); wave w does rows w, w+8, .., w+56
    auto stage = [&](int t, __bf16* xb) {
        #pragma unroll
        for (int rr = 0; rr < 8; ++rr) {
            const int r = wave + (rr << 3);          // r&7 == wave
            const int idxv = inputs[(r0 + r) * T_LEN + t];
            const float* er = emb + (size_t)idxv * EMB_D;
            const int k0 = lane;                     // < 100 always
            xb[(r << 7) + ((((k0 >> 3) ^ (r & 7)) << 3) | (k0 & 7))] = (__bf16)er[k0];
            const int k1 = lane + 64;
            if (k1 < EMB_D)
                xb[(r << 7) + ((((k1 >> 3) ^ (r & 7)) << 3) | (k1 & 7))] = (__bf16)er[k1];
        }
    };

    // pipeline prologue
    PF(0, pA); PF(1, pB);

    stage(0, xbuf[0]);
    __syncthreads();

    #pragma unroll 1
    for (int t = 0; t < T_LEN; t += 2) {
        stage(t + 1, xbuf[1]);      // t+1 <= 79; overlaps STEP's read phase
        STEP(xbuf[0]);
        if (t + 2 < T_LEN) stage(t + 2, xbuf[0]);
        STEP(xbuf[1]);
    }
    // h_last in hb, rows 0..63

    // output head: wave w reduces rows 8w .. 8w+7
    #pragma unroll
    for (int rr = 0; rr < 8; ++rr) {
        const int m = (wave << 3) + rr;
        const bf16x8 hv = *(const bf16x8*)&hb[(m << 9) + ((lane ^ (m & 7)) << 3)];
        float s = 0.0f;
        #pragma unroll
        for (int j = 0; j < 8; ++j)
            s += (float)hv[j] * Wout[(lane << 3) + j];
        #pragma unroll
        for (int off = 32; off > 0; off >>= 1)
            s += __shfl_down(s, off, 64);
        if (lane == 0) {
            const float logit = s + bout[0];
            out[r0 + m] = __builtin_amdgcn_rcpf(
                1.0f + __builtin_amdgcn_exp2f(-logit * 1.4426950408889634f));
        }
    }
}

extern "C" void kernel_launch(void* const* d_in, const int* in_sizes, int n_in,
                              void* d_out, int out_size, void* d_ws, size_t ws_size,
                              hipStream_t stream) {
    __bf16* FW = (__bf16*)d_ws;                 // 512*512*2 = 512 KB (frag order)
    __bf16* FX = FW + UNITS * UNITS;            // 512*128*2 = 128 KB (frag order)
    prep_kernel<<<dim3(160), dim3(256), 0, stream>>>(
        (const float*)d_in[3],   // W_hh
        (const float*)d_in[2],   // W_xh
        FW, FX);
    rnn_kernel<<<dim3(NBLK), dim3(NTHR), 0, stream>>>(
        (const int*)d_in[0],     // inputs
        (const float*)d_in[1],   // emb_table
        (const float*)d_in[4],   // b_h
        (const float*)d_in[5],   // W_out
        (const float*)d_in[6],   // b_out
        FW, FX,
        (float*)d_out);
}